// Round 2
// baseline (448.945 us; speedup 1.0000x reference)
//
#include <hip/hip_runtime.h>
#include <math.h>

#define BSZ 32
#define SEQ 2048
#define HID 1024
#define OUTD 1024
#define K2  (HID + OUTD)   // 2048

// ---------------- q = hidden @ W1^T  -> q[b*OUTD + o] ----------------
// wave per (o,b), o-major: consecutive waves share the W1 row (L1/L2 reuse).
__global__ void q_kernel(const float* __restrict__ hidden,
                         const float* __restrict__ W1,
                         float* __restrict__ q) {
    int gid  = blockIdx.x * blockDim.x + threadIdx.x;
    int wave = gid >> 6;
    int lane = threadIdx.x & 63;
    if (wave >= OUTD * BSZ) return;
    int o = wave >> 5;        // / 32
    int b = wave & 31;
    const float* w = W1 + (size_t)o * HID;
    const float* h = hidden + (size_t)b * HID;
    float acc = 0.f;
#pragma unroll
    for (int it = 0; it < HID / 256; ++it) {
        int k = it * 256 + lane * 4;
        float4 wv = *reinterpret_cast<const float4*>(w + k);
        float4 hv = *reinterpret_cast<const float4*>(h + k);
        acc += wv.x * hv.x + wv.y * hv.y + wv.z * hv.z + wv.w * hv.w;
    }
#pragma unroll
    for (int off = 32; off; off >>= 1) acc += __shfl_down(acc, off);
    if (lane == 0) q[b * OUTD + o] = acc;
}

// ---------------- att[b,s] = enc[b,s,:] . q[b,:] ----------------
// wave per row (b,s); 4KB coalesced row read.
__global__ void scores_kernel(const float* __restrict__ enc,
                              const float* __restrict__ q,
                              float* __restrict__ att) {
    int gid  = blockIdx.x * blockDim.x + threadIdx.x;
    int wave = gid >> 6;
    int lane = threadIdx.x & 63;
    if (wave >= BSZ * SEQ) return;
    int b = wave >> 11;       // / SEQ
    const float* row = enc + (size_t)wave * HID;
    const float* qb  = q + (size_t)b * OUTD;
    float acc = 0.f;
#pragma unroll
    for (int it = 0; it < HID / 256; ++it) {
        int k = it * 256 + lane * 4;
        float4 e  = *reinterpret_cast<const float4*>(row + k);
        float4 qq = *reinterpret_cast<const float4*>(qb + k);
        acc += e.x * qq.x + e.y * qq.y + e.z * qq.z + e.w * qq.w;
    }
#pragma unroll
    for (int off = 32; off; off >>= 1) acc += __shfl_down(acc, off);
    if (lane == 0) att[wave] = acc;
}

// ---------------- masked softmax over S, per batch ----------------
// One block (256 threads) per b. Replicates the torch quirk:
// masked = (s<len) ? att : 0 ; if (masked == 0) masked = -1e10.
// Writes normalized attn in-place over att (ws) and attn.T into out tail.
__global__ void softmax_kernel(float* __restrict__ att,
                               const int* __restrict__ src_lens,
                               float* __restrict__ attn_t) {
    int b   = blockIdx.x;
    int len = src_lens[b];
    int tid = threadIdx.x;
    float vals[SEQ / 256];
    float m = -INFINITY;
#pragma unroll
    for (int i = 0; i < SEQ / 256; ++i) {
        int s = tid + i * 256;
        float a = att[b * SEQ + s];
        float masked = (s < len) ? a : 0.f;
        if (masked == 0.f) masked = -1e10f;
        vals[i] = masked;
        m = fmaxf(m, masked);
    }
#pragma unroll
    for (int off = 32; off; off >>= 1) m = fmaxf(m, __shfl_down(m, off));
    __shared__ float sm[4];
    if ((tid & 63) == 0) sm[tid >> 6] = m;
    __syncthreads();
    float bm = fmaxf(fmaxf(sm[0], sm[1]), fmaxf(sm[2], sm[3]));
    float sum = 0.f;
#pragma unroll
    for (int i = 0; i < SEQ / 256; ++i) {
        vals[i] = expf(vals[i] - bm);
        sum += vals[i];
    }
#pragma unroll
    for (int off = 32; off; off >>= 1) sum += __shfl_down(sum, off);
    __shared__ float ss[4];
    if ((tid & 63) == 0) ss[tid >> 6] = sum;
    __syncthreads();
    float inv = 1.f / (ss[0] + ss[1] + ss[2] + ss[3]);
#pragma unroll
    for (int i = 0; i < SEQ / 256; ++i) {
        int s = tid + i * 256;
        float p = vals[i] * inv;
        att[b * SEQ + s]    = p;          // normalized attn, [b,s] layout (ws)
        attn_t[s * BSZ + b] = p;          // output: attn.T  [S,B]
    }
}

// ---------------- ctx[b,d] = sum_s attn[b,s] * enc[b,s,d] ----------------
// Grid = BSZ * NCHUNK blocks; each block reduces SCHUNK s-steps for all 1024 d
// (thread t owns d = 4t..4t+3), then atomicAdd into zeroed ctx.
#define NCHUNK 32
#define SCHUNK (SEQ / NCHUNK)   // 64
__global__ void ctx_kernel(const float* __restrict__ enc,
                           const float* __restrict__ attn,
                           float* __restrict__ ctx) {
    int b     = blockIdx.x >> 5;     // / NCHUNK
    int chunk = blockIdx.x & (NCHUNK - 1);
    int s0    = chunk * SCHUNK;
    int d0    = threadIdx.x * 4;
    const float* base = enc + ((size_t)b * SEQ + s0) * HID + d0;
    float4 acc = make_float4(0.f, 0.f, 0.f, 0.f);
#pragma unroll 4
    for (int i = 0; i < SCHUNK; ++i) {
        float p  = attn[b * SEQ + s0 + i];
        float4 v = *reinterpret_cast<const float4*>(base + (size_t)i * HID);
        acc.x += p * v.x; acc.y += p * v.y; acc.z += p * v.z; acc.w += p * v.w;
    }
    float* c = ctx + b * OUTD + d0;
    atomicAdd(c + 0, acc.x);
    atomicAdd(c + 1, acc.y);
    atomicAdd(c + 2, acc.z);
    atomicAdd(c + 3, acc.w);
}

// ---------------- out = tanh(concat([ctx, hidden]) @ W2^T) ----------------
// wave per (o,b), o-major: W2 row reused across the 32 b's -> W2 streams once.
__global__ void out_kernel(const float* __restrict__ ctx,
                           const float* __restrict__ hidden,
                           const float* __restrict__ W2,
                           float* __restrict__ out) {
    int gid  = blockIdx.x * blockDim.x + threadIdx.x;
    int wave = gid >> 6;
    int lane = threadIdx.x & 63;
    if (wave >= OUTD * BSZ) return;
    int o = wave >> 5;
    int b = wave & 31;
    const float* w = W2 + (size_t)o * K2;
    float acc = 0.f;
#pragma unroll
    for (int it = 0; it < HID / 256; ++it) {
        int k = it * 256 + lane * 4;
        float4 wv = *reinterpret_cast<const float4*>(w + k);
        float4 cv = *reinterpret_cast<const float4*>(ctx + (size_t)b * HID + k);
        acc += wv.x * cv.x + wv.y * cv.y + wv.z * cv.z + wv.w * cv.w;
    }
#pragma unroll
    for (int it = 0; it < HID / 256; ++it) {
        int k = it * 256 + lane * 4;
        float4 wv = *reinterpret_cast<const float4*>(w + HID + k);
        float4 hv = *reinterpret_cast<const float4*>(hidden + (size_t)b * HID + k);
        acc += wv.x * hv.x + wv.y * hv.y + wv.z * hv.z + wv.w * hv.w;
    }
#pragma unroll
    for (int off = 32; off; off >>= 1) acc += __shfl_down(acc, off);
    if (lane == 0) out[b * OUTD + o] = tanhf(acc);
}

extern "C" void kernel_launch(void* const* d_in, const int* in_sizes, int n_in,
                              void* d_out, int out_size, void* d_ws, size_t ws_size,
                              hipStream_t stream) {
    const float* hidden = (const float*)d_in[0];   // [32,1024]
    const float* enc    = (const float*)d_in[1];   // [32,2048,1024]
    const int*   lens   = (const int*)d_in[2];     // [32]
    const float* W1     = (const float*)d_in[3];   // [1024,1024]
    const float* W2     = (const float*)d_in[4];   // [1024,2048]

    float* out    = (float*)d_out;                 // [32,1024] then attn.T [2048,32]
    float* attn_t = out + BSZ * OUTD;

    // workspace layout (floats): q | att/attn | ctx
    float* q   = (float*)d_ws;                     // 32768
    float* att = q + BSZ * OUTD;                   // 65536
    float* ctx = att + BSZ * SEQ;                  // 32768

    // zero ctx for atomic accumulation (ws is poisoned 0xAA before every call)
    hipMemsetAsync(ctx, 0, (size_t)BSZ * OUTD * sizeof(float), stream);

    // 1. q = hidden @ W1^T
    q_kernel<<<(OUTD * BSZ * 64) / 256, 256, 0, stream>>>(hidden, W1, q);
    // 2. raw scores
    scores_kernel<<<(BSZ * SEQ * 64) / 256, 256, 0, stream>>>(enc, q, att);
    // 3. masked softmax (+ attn.T output)
    softmax_kernel<<<BSZ, 256, 0, stream>>>(att, lens, attn_t);
    // 4. ctx = attn @ enc
    ctx_kernel<<<BSZ * NCHUNK, 256, 0, stream>>>(enc, att, ctx);
    // 5. out = tanh(concat @ W2^T)
    out_kernel<<<(OUTD * BSZ * 64) / 256, 256, 0, stream>>>(ctx, hidden, W2, out);
}

// Round 3
// 420.207 us; speedup vs baseline: 1.0684x; 1.0684x over previous
//
#include <hip/hip_runtime.h>
#include <math.h>

#define BSZ 32
#define SEQ 2048
#define HID 1024
#define OUTD 1024
#define K2  (HID + OUTD)   // 2048

__device__ __forceinline__ float wave_reduce(float v) {
#pragma unroll
    for (int off = 32; off; off >>= 1) v += __shfl_down(v, off);
    return v;
}

// ---------------- q = hidden @ W1^T -> q[b*OUTD + o] ----------------
// Block = 256 thr = 4 waves = 4 b's; block owns 8 o's. hidden row lives in
// 4 float4 regs; the 4 waves stream the same 8 W1 rows (L1 hit-share).
// grid = (OUTD/8) * (BSZ/4) = 128*8 = 1024 blocks.
__global__ void q_kernel(const float* __restrict__ hidden,
                         const float* __restrict__ W1,
                         float* __restrict__ q) {
    int og   = blockIdx.x >> 3;        // 0..127 (8 o's each)
    int bg   = blockIdx.x & 7;         // 0..7   (4 b's each)
    int wave = threadIdx.x >> 6;
    int lane = threadIdx.x & 63;
    int b    = bg * 4 + wave;
    const float* h = hidden + (size_t)b * HID;
    float4 hv[4];
#pragma unroll
    for (int j = 0; j < 4; ++j)
        hv[j] = *reinterpret_cast<const float4*>(h + j * 256 + lane * 4);
#pragma unroll
    for (int oi = 0; oi < 8; ++oi) {
        int o = og * 8 + oi;
        const float* w = W1 + (size_t)o * HID;
        float acc = 0.f;
#pragma unroll
        for (int j = 0; j < 4; ++j) {
            float4 wv = *reinterpret_cast<const float4*>(w + j * 256 + lane * 4);
            acc += wv.x * hv[j].x + wv.y * hv[j].y + wv.z * hv[j].z + wv.w * hv[j].w;
        }
        acc = wave_reduce(acc);
        if (lane == 0) q[b * OUTD + o] = acc;
    }
}

// ---------------- att[b,s] = enc[b,s,:] . q[b,:] ----------------
// wave per row (b,s). Rows s >= len[b] are masked to -1e10 downstream no
// matter their value -> skip the 4KB read entirely (~25% traffic cut).
__global__ void scores_kernel(const float* __restrict__ enc,
                              const float* __restrict__ q,
                              const int* __restrict__ src_lens,
                              float* __restrict__ att) {
    int gid  = blockIdx.x * blockDim.x + threadIdx.x;
    int wave = gid >> 6;
    int lane = threadIdx.x & 63;
    if (wave >= BSZ * SEQ) return;
    int b = wave >> 11;       // / SEQ
    int s = wave & (SEQ - 1);
    if (s >= src_lens[b]) return;   // masked row: att value irrelevant
    const float* row = enc + (size_t)wave * HID;
    const float* qb  = q + (size_t)b * OUTD;
    float acc = 0.f;
#pragma unroll
    for (int it = 0; it < HID / 256; ++it) {
        int k = it * 256 + lane * 4;
        float4 e  = *reinterpret_cast<const float4*>(row + k);
        float4 qq = *reinterpret_cast<const float4*>(qb + k);
        acc += e.x * qq.x + e.y * qq.y + e.z * qq.z + e.w * qq.w;
    }
    acc = wave_reduce(acc);
    if (lane == 0) att[wave] = acc;
}

// ---------------- masked softmax over S, per batch ----------------
// One block (256 threads) per b. torch quirk: masked = (s<len)?att:0;
// masked==0 -> -1e10. Writes normalized attn in-place (ws) + attn.T (out).
__global__ void softmax_kernel(float* __restrict__ att,
                               const int* __restrict__ src_lens,
                               float* __restrict__ attn_t) {
    int b   = blockIdx.x;
    int len = src_lens[b];
    int tid = threadIdx.x;
    float vals[SEQ / 256];
    float m = -INFINITY;
#pragma unroll
    for (int i = 0; i < SEQ / 256; ++i) {
        int s = tid + i * 256;
        float a = att[b * SEQ + s];          // garbage for s>=len, unused
        float masked = (s < len) ? a : 0.f;
        if (masked == 0.f) masked = -1e10f;
        vals[i] = masked;
        m = fmaxf(m, masked);
    }
#pragma unroll
    for (int off = 32; off; off >>= 1) m = fmaxf(m, __shfl_down(m, off));
    __shared__ float sm[4];
    if ((tid & 63) == 0) sm[tid >> 6] = m;
    __syncthreads();
    float bm = fmaxf(fmaxf(sm[0], sm[1]), fmaxf(sm[2], sm[3]));
    float sum = 0.f;
#pragma unroll
    for (int i = 0; i < SEQ / 256; ++i) {
        vals[i] = expf(vals[i] - bm);        // exp(-1e10-bm) underflows to 0
        sum += vals[i];
    }
    sum = wave_reduce(sum);
    __shared__ float ss[4];
    if ((tid & 63) == 0) ss[tid >> 6] = sum;
    __syncthreads();
    float inv = 1.f / (ss[0] + ss[1] + ss[2] + ss[3]);
#pragma unroll
    for (int i = 0; i < SEQ / 256; ++i) {
        int s = tid + i * 256;
        float p = vals[i] * inv;
        att[b * SEQ + s]    = p;          // normalized attn [b,s] (ws)
        attn_t[s * BSZ + b] = p;          // output attn.T [S,B]
    }
}

// ---------------- ctx[b,d] = sum_s attn[b,s] * enc[b,s,d] ----------------
// Grid = BSZ*NCHUNK blocks; block reduces its s-chunk (clamped to len[b];
// p==0 beyond len) for all 1024 d, atomicAdd into zeroed ctx.
#define NCHUNK 64
#define SCHUNK (SEQ / NCHUNK)   // 32
__global__ void ctx_kernel(const float* __restrict__ enc,
                           const float* __restrict__ attn,
                           const int* __restrict__ src_lens,
                           float* __restrict__ ctx) {
    int b     = blockIdx.x >> 6;          // / NCHUNK
    int chunk = blockIdx.x & (NCHUNK - 1);
    int s0    = chunk * SCHUNK;
    int n     = src_lens[b] - s0;
    if (n <= 0) return;                    // fully-masked chunk: p == 0
    if (n > SCHUNK) n = SCHUNK;
    int d0    = threadIdx.x * 4;
    const float* base = enc + ((size_t)b * SEQ + s0) * HID + d0;
    float4 acc = make_float4(0.f, 0.f, 0.f, 0.f);
#pragma unroll 4
    for (int i = 0; i < n; ++i) {
        float p  = attn[b * SEQ + s0 + i];
        float4 v = *reinterpret_cast<const float4*>(base + (size_t)i * HID);
        acc.x += p * v.x; acc.y += p * v.y; acc.z += p * v.z; acc.w += p * v.w;
    }
    float* c = ctx + b * OUTD + d0;
    atomicAdd(c + 0, acc.x);
    atomicAdd(c + 1, acc.y);
    atomicAdd(c + 2, acc.z);
    atomicAdd(c + 3, acc.w);
}

// ---------------- out = tanh(concat([ctx, hidden]) @ W2^T) ----------------
// Block = 4 waves = 4 b's, owns 8 o's. concat row in 8 float4 regs; the 4
// waves stream the same 8 W2 rows (L1 share; 8 bg-blocks share via L2).
// grid = (OUTD/8) * (BSZ/4) = 1024 blocks. W2 read ~once from HBM.
__global__ void out_kernel(const float* __restrict__ ctx,
                           const float* __restrict__ hidden,
                           const float* __restrict__ W2,
                           float* __restrict__ out) {
    int og   = blockIdx.x >> 3;
    int bg   = blockIdx.x & 7;
    int wave = threadIdx.x >> 6;
    int lane = threadIdx.x & 63;
    int b    = bg * 4 + wave;
    float4 cv[4], hv[4];
#pragma unroll
    for (int j = 0; j < 4; ++j) {
        cv[j] = *reinterpret_cast<const float4*>(ctx    + (size_t)b * HID + j * 256 + lane * 4);
        hv[j] = *reinterpret_cast<const float4*>(hidden + (size_t)b * HID + j * 256 + lane * 4);
    }
#pragma unroll
    for (int oi = 0; oi < 8; ++oi) {
        int o = og * 8 + oi;
        const float* w = W2 + (size_t)o * K2;
        float acc = 0.f;
#pragma unroll
        for (int j = 0; j < 4; ++j) {
            float4 wv = *reinterpret_cast<const float4*>(w + j * 256 + lane * 4);
            acc += wv.x * cv[j].x + wv.y * cv[j].y + wv.z * cv[j].z + wv.w * cv[j].w;
        }
#pragma unroll
        for (int j = 0; j < 4; ++j) {
            float4 wv = *reinterpret_cast<const float4*>(w + HID + j * 256 + lane * 4);
            acc += wv.x * hv[j].x + wv.y * hv[j].y + wv.z * hv[j].z + wv.w * hv[j].w;
        }
        acc = wave_reduce(acc);
        if (lane == 0) out[b * OUTD + o] = tanhf(acc);
    }
}

extern "C" void kernel_launch(void* const* d_in, const int* in_sizes, int n_in,
                              void* d_out, int out_size, void* d_ws, size_t ws_size,
                              hipStream_t stream) {
    const float* hidden = (const float*)d_in[0];   // [32,1024]
    const float* enc    = (const float*)d_in[1];   // [32,2048,1024]
    const int*   lens   = (const int*)d_in[2];     // [32]
    const float* W1     = (const float*)d_in[3];   // [1024,1024]
    const float* W2     = (const float*)d_in[4];   // [1024,2048]

    float* out    = (float*)d_out;                 // [32,1024] then attn.T [2048,32]
    float* attn_t = out + BSZ * OUTD;

    // workspace layout (floats): q | att/attn | ctx
    float* q   = (float*)d_ws;                     // 32768
    float* att = q + BSZ * OUTD;                   // 65536
    float* ctx = att + BSZ * SEQ;                  // 32768

    hipMemsetAsync(ctx, 0, (size_t)BSZ * OUTD * sizeof(float), stream);

    q_kernel<<<(OUTD / 8) * (BSZ / 4), 256, 0, stream>>>(hidden, W1, q);
    scores_kernel<<<(BSZ * SEQ * 64) / 256, 256, 0, stream>>>(enc, q, lens, att);
    softmax_kernel<<<BSZ, 256, 0, stream>>>(att, lens, attn_t);
    ctx_kernel<<<BSZ * NCHUNK, 256, 0, stream>>>(enc, att, lens, ctx);
    out_kernel<<<(OUTD / 8) * (BSZ / 4), 256, 0, stream>>>(ctx, hidden, W2, out);
}